// Round 6
// baseline (83.474 us; speedup 1.0000x reference)
//
#include <hip/hip_runtime.h>
#include <hip/hip_bf16.h>
#include <stdint.h>

#define MDIM 1024
#define NDIM 4096
#define KDIM 4096

#define BM 128
#define BN 64
#define BK 64

typedef __attribute__((ext_vector_type(4))) float f32x4;
typedef __attribute__((ext_vector_type(4))) float float4v;
typedef __attribute__((ext_vector_type(4))) int int4v;
typedef __attribute__((ext_vector_type(4))) unsigned int uint4v;
typedef __attribute__((ext_vector_type(8))) short short8;

#define GLOBAL_AS __attribute__((address_space(1)))
#define LDS_AS __attribute__((address_space(3)))

// Hardened barrier (rule #18): sched_barrier(0) on BOTH sides + lgkmcnt(0)
// drain. Proven race-free in rounds 5's bench (cold + L2-warm replay).
#define HARD_BARRIER() do {                               \
    __builtin_amdgcn_sched_barrier(0);                    \
    asm volatile("s_waitcnt lgkmcnt(0)" ::: "memory");    \
    __builtin_amdgcn_s_barrier();                         \
    asm volatile("" ::: "memory");                        \
    __builtin_amdgcn_sched_barrier(0);                    \
} while (0)

__device__ __constant__ float c_nf4[16] = {
    -1.0f, -0.6961928009986877f, -0.5250730514526367f, -0.39491748809814453f,
    -0.28444138169288635f, -0.18477343022823334f, -0.09105003625154495f, 0.0f,
    0.07958029955625534f, 0.16093020141124725f, 0.24611230194568634f,
    0.33791524171829224f, 0.44070982933044434f, 0.5626170039176941f,
    0.7229568362236023f, 1.0f};

__device__ __forceinline__ unsigned bf16_rne(float f) {
    unsigned u = __float_as_uint(f);
    return (u + 0x7fffu + ((u >> 16) & 1u)) >> 16;
}

// ---------------------------------------------------------------------------
// Prep: Wc = bf16(w0 + NF4[idx]*scale + zp); xb = bf16(x)
// ---------------------------------------------------------------------------
#define W_BLOCKS ((NDIM * KDIM) / (256 * 8))   // 8192
#define X_BLOCKS ((MDIM * KDIM) / (256 * 8))   // 2048

__global__ __launch_bounds__(256) void prep_kernel(
    const float* __restrict__ x, const float* __restrict__ w0,
    const int* __restrict__ nf4_idx, const float* __restrict__ scale_p,
    const float* __restrict__ zp_p, __hip_bfloat16* __restrict__ Wc,
    __hip_bfloat16* __restrict__ xb)
{
    const int lane = threadIdx.x & 63;
    if (blockIdx.x < W_BLOCKS) {
        const float scale = scale_p[0];
        const float zp = zp_p[0];
        const int tab = __float_as_int(c_nf4[lane & 15] * scale + zp);
        const size_t base = ((size_t)blockIdx.x * 256 + threadIdx.x) * 8;
        int4v i0 = *(const int4v*)(nf4_idx + base);
        int4v i1 = *(const int4v*)(nf4_idx + base + 4);
        float4v w_0 = *(const float4v*)(w0 + base);
        float4v w_1 = *(const float4v*)(w0 + base + 4);
        unsigned r[8];
#pragma unroll
        for (int j = 0; j < 4; j++) {
            float q = __int_as_float(__builtin_amdgcn_ds_bpermute(i0[j] * 4, tab));
            r[j] = bf16_rne(w_0[j] + q);
        }
#pragma unroll
        for (int j = 0; j < 4; j++) {
            float q = __int_as_float(__builtin_amdgcn_ds_bpermute(i1[j] * 4, tab));
            r[4 + j] = bf16_rne(w_1[j] + q);
        }
        uint4v st;
        st.x = r[0] | (r[1] << 16);
        st.y = r[2] | (r[3] << 16);
        st.z = r[4] | (r[5] << 16);
        st.w = r[6] | (r[7] << 16);
        *(uint4v*)((unsigned short*)Wc + base) = st;
    } else {
        const size_t base = ((size_t)(blockIdx.x - W_BLOCKS) * 256 + threadIdx.x) * 8;
        float4v a0 = *(const float4v*)(x + base);
        float4v a1 = *(const float4v*)(x + base + 4);
        uint4v st;
        st.x = bf16_rne(a0[0]) | (bf16_rne(a0[1]) << 16);
        st.y = bf16_rne(a0[2]) | (bf16_rne(a0[3]) << 16);
        st.z = bf16_rne(a1[0]) | (bf16_rne(a1[1]) << 16);
        st.w = bf16_rne(a1[2]) | (bf16_rne(a1[3]) << 16);
        *(uint4v*)((unsigned short*)xb + base) = st;
    }
}

// ---------------------------------------------------------------------------
// GEMM: C[m][n] = sum_k A[m][k] * B[n][k]   (A,B bf16 row-major, C fp32)
// 128x64 tile, BK=64, 4 waves as 2m x 2k: each wave computes 64x64 output
// over HALF of each BK step -> 8 ds_read_b128 feed 16 MFMAs (32 FLOP/LDS-B).
// Grid 512 = 2 blocks/CU (72 KB LDS each): independent barrier domains give
// cross-block MFMA/stall overlap (the round-5 1-block/CU structure had none).
// Triple-buffered LDS, prefetch distance 2, counted vmcnt(12).
// XOR chunk swizzle via pre-swizzled global source (LDS linear, rule #21).
// XCD remap: 64 blocks/XCD -> per-XCD Wc panel 4 MB (L2-resident).
// ---------------------------------------------------------------------------
__global__ __launch_bounds__(256, 2) void gemm_kernel(
    const __hip_bfloat16* __restrict__ A,   // [MDIM][KDIM]
    const __hip_bfloat16* __restrict__ B,   // [NDIM][KDIM]
    float* __restrict__ C)                  // [MDIM][NDIM]
{
    __shared__ __hip_bfloat16 smA[3][BM * BK];   // 48 KB
    __shared__ __hip_bfloat16 smB[3][BN * BK];   // 24 KB

    const int tid = threadIdx.x;
    const int lane = tid & 63;
    const int w = tid >> 6;          // wave 0..3
    const int wr = w >> 1;           // 0..1 -> m-offset 64
    const int wk = w & 1;            // 0..1 -> k-half within BK

    // XCD remap: orig = (bid%8)*64 + bid/8 -> XCD x owns ntiles [x*8, x*8+8)
    // x all 8 mtiles (Wc panel 4 MB, L2-resident; nwg=512 % 8 == 0, bijective)
    const int bid = blockIdx.x;
    const int orig = (bid & 7) * 64 + (bid >> 3);
    const int mtile = orig & 7;      // 0..7
    const int ntile = orig >> 3;     // 0..63

    // --- staging addresses (per-lane global source, pre-swizzled) ---
    // A: wave w stages rows [w*32, w*32+32): 4 instrs (8 rows each).
    // B: wave w stages rows [w*16, w*16+16): 2 instrs.
    const int s_subrow = lane >> 3;
    const int s_chunkpos = lane & 7;
    int a_row[4], a_goff[4], b_row[2], b_goff[2];
#pragma unroll
    for (int j = 0; j < 4; j++) {
        int row = w * 32 + j * 8 + s_subrow;
        a_row[j] = row;
        a_goff[j] = (s_chunkpos ^ (row & 7)) * 8;
    }
#pragma unroll
    for (int j = 0; j < 2; j++) {
        int row = w * 16 + j * 8 + s_subrow;
        b_row[j] = row;
        b_goff[j] = (s_chunkpos ^ (row & 7)) * 8;
    }

#define STAGE(buf, kt) do {                                                        \
    _Pragma("unroll")                                                              \
    for (int j = 0; j < 4; j++) {                                                  \
        const __hip_bfloat16* ga = A + (size_t)(mtile * BM + a_row[j]) * KDIM      \
                                     + (kt) * BK + a_goff[j];                      \
        __builtin_amdgcn_global_load_lds((const GLOBAL_AS void*)ga,                \
            (LDS_AS void*)&smA[buf][(w * 32 + j * 8) * BK], 16, 0, 0);             \
    }                                                                              \
    _Pragma("unroll")                                                              \
    for (int j = 0; j < 2; j++) {                                                  \
        const __hip_bfloat16* gb = B + (size_t)(ntile * BN + b_row[j]) * KDIM      \
                                     + (kt) * BK + b_goff[j];                      \
        __builtin_amdgcn_global_load_lds((const GLOBAL_AS void*)gb,                \
            (LDS_AS void*)&smB[buf][(w * 16 + j * 8) * BK], 16, 0, 0);             \
    }                                                                              \
} while (0)

    // --- fragment LDS element offsets (swizzled reads) ---
    // 16x16x32 frag at k-chunk = wk*32: lane holds [row][k=(lane>>4)*8 ..+8]
    int a_off[4], b_off[4];
#pragma unroll
    for (int m = 0; m < 4; m++) {
        int row = wr * 64 + m * 16 + (lane & 15);
        int c = wk * 4 + (lane >> 4);
        a_off[m] = row * BK + (c ^ (row & 7)) * 8;
    }
#pragma unroll
    for (int n = 0; n < 4; n++) {
        int row = n * 16 + (lane & 15);
        int c = wk * 4 + (lane >> 4);
        b_off[n] = row * BK + (c ^ (row & 7)) * 8;
    }

    f32x4 acc[4][4] = {};

#define COMPUTE(buf) do {                                                          \
    short8 af[4], bfv[4];                                                          \
    _Pragma("unroll")                                                              \
    for (int m = 0; m < 4; m++)                                                    \
        af[m] = *(const short8*)&smA[buf][a_off[m]];                               \
    _Pragma("unroll")                                                              \
    for (int n = 0; n < 4; n++)                                                    \
        bfv[n] = *(const short8*)&smB[buf][b_off[n]];                              \
    _Pragma("unroll")                                                              \
    for (int m = 0; m < 4; m++)                                                    \
        _Pragma("unroll")                                                          \
        for (int n = 0; n < 4; n++)                                                \
            acc[m][n] = __builtin_amdgcn_mfma_f32_16x16x32_bf16(                   \
                af[m], bfv[n], acc[m][n], 0, 0, 0);                                \
} while (0)

    const int NT = KDIM / BK;  // 64
    STAGE(0, 0);
    STAGE(1, 1);

    for (int t = 0; t < NT; t++) {
        const int cur = t % 3;
        // STAGE(t+2) overwrites buf[(t-1)%3]; its readers finished at the
        // trailing barrier of iteration t-1 (sched_barrier'd, no hoisting).
        if (t + 2 < NT) {
            STAGE((t + 2) % 3, t + 2);
            // per-wave 6 loads/stage; stages t+1,t+2 in flight (12) ->
            // oldest stage (t) has landed.
            asm volatile("s_waitcnt vmcnt(12)" ::: "memory");
        } else if (t + 1 < NT) {
            asm volatile("s_waitcnt vmcnt(6)" ::: "memory");
        } else {
            asm volatile("s_waitcnt vmcnt(0)" ::: "memory");
        }
        HARD_BARRIER();        // all waves' stage(t) visible
        COMPUTE(cur);
        HARD_BARRIER();        // all waves done reading buf[cur] before restage
    }

    // --- cross-wk reduction through LDS (staging buffers are dead now) ---
    // wk=1 wave writes its 64 acc floats lane-minor (16B/lane, 2-way = free):
    // float offset = pair*4096 + (m*4+n)*256 + lane*4
    float* red = (float*)&smA[0][0];         // 32 KB used of 72 KB
    const int pair = wr;                     // 0..1
    if (wk == 1) {
#pragma unroll
        for (int m = 0; m < 4; m++) {
#pragma unroll
            for (int n = 0; n < 4; n++) {
                *(f32x4*)&red[pair * 4096 + (m * 4 + n) * 256 + lane * 4] =
                    acc[m][n];
            }
        }
    }
    HARD_BARRIER();   // includes lgkmcnt(0) drain -> writes visible
    if (wk == 0) {
        // epilogue: C/D layout col = lane&15, row = (lane>>4)*4 + r
        const int rbase = mtile * BM + wr * 64 + ((lane >> 4) << 2);
        const int cbase = ntile * BN + (lane & 15);
#pragma unroll
        for (int m = 0; m < 4; m++) {
#pragma unroll
            for (int n = 0; n < 4; n++) {
                f32x4 other =
                    *(const f32x4*)&red[pair * 4096 + (m * 4 + n) * 256 + lane * 4];
                f32x4 v = acc[m][n] + other;
#pragma unroll
                for (int r = 0; r < 4; r++) {
                    C[(size_t)(rbase + m * 16 + r) * NDIM + cbase + n * 16] = v[r];
                }
            }
        }
    }
#undef STAGE
#undef COMPUTE
}

// ---------------------------------------------------------------------------
// Fallback (only if ws too small): textbook fp32 tiled GEMM with inline dequant
// ---------------------------------------------------------------------------
__global__ void fallback_kernel(const float* __restrict__ x,
                                const float* __restrict__ w0,
                                const int* __restrict__ nf4_idx,
                                const float* __restrict__ sp,
                                const float* __restrict__ zpp,
                                float* __restrict__ out)
{
    __shared__ float As[16][16], Bs[16][17];
    const int tx = threadIdx.x, ty = threadIdx.y;
    const int n0 = blockIdx.x * 16, m0 = blockIdx.y * 16;
    const float s = sp[0], zp = zpp[0];
    float acc = 0.0f;
    for (int k0 = 0; k0 < KDIM; k0 += 16) {
        As[ty][tx] = x[(size_t)(m0 + ty) * KDIM + k0 + tx];
        int id = nf4_idx[(size_t)(n0 + ty) * KDIM + k0 + tx];
        Bs[ty][tx] = w0[(size_t)(n0 + ty) * KDIM + k0 + tx] + c_nf4[id] * s + zp;
        __syncthreads();
#pragma unroll
        for (int j = 0; j < 16; j++) acc += As[ty][j] * Bs[tx][j];
        __syncthreads();
    }
    out[(size_t)(m0 + ty) * NDIM + n0 + tx] = acc;
}

extern "C" void kernel_launch(void* const* d_in, const int* in_sizes, int n_in,
                              void* d_out, int out_size, void* d_ws, size_t ws_size,
                              hipStream_t stream) {
    const float* x = (const float*)d_in[0];
    const float* w0 = (const float*)d_in[1];
    const int* nf4_idx = (const int*)d_in[2];
    const float* scale = (const float*)d_in[3];
    const float* zp = (const float*)d_in[4];
    float* out = (float*)d_out;

    const size_t wc_bytes = (size_t)NDIM * KDIM * 2;       // 33,554,432
    const size_t xb_bytes = (size_t)MDIM * KDIM * 2;       //  8,388,608

    if (ws_size >= wc_bytes + xb_bytes) {
        __hip_bfloat16* Wc = (__hip_bfloat16*)d_ws;
        __hip_bfloat16* xb = (__hip_bfloat16*)((char*)d_ws + wc_bytes);
        prep_kernel<<<W_BLOCKS + X_BLOCKS, 256, 0, stream>>>(
            x, w0, nf4_idx, scale, zp, Wc, xb);
        gemm_kernel<<<(MDIM / BM) * (NDIM / BN), 256, 0, stream>>>(xb, Wc, out);
    } else {
        fallback_kernel<<<dim3(NDIM / 16, MDIM / 16), dim3(16, 16), 0, stream>>>(
            x, w0, nf4_idx, scale, zp, out);
    }
}

// Round 7
// 77.249 us; speedup vs baseline: 1.0806x; 1.0806x over previous
//
#include <hip/hip_runtime.h>
#include <hip/hip_bf16.h>
#include <stdint.h>

#define MDIM 1024
#define NDIM 4096
#define KDIM 4096

#define BM 128
#define BN 128
#define BK 128
#define NT (KDIM / BK)   // 32

typedef __attribute__((ext_vector_type(4))) float f32x4;
typedef __attribute__((ext_vector_type(4))) float float4v;
typedef __attribute__((ext_vector_type(4))) int int4v;
typedef __attribute__((ext_vector_type(4))) unsigned int uint4v;
typedef __attribute__((ext_vector_type(8))) short short8;

#define GLOBAL_AS __attribute__((address_space(1)))
#define LDS_AS __attribute__((address_space(3)))

// Hardened barrier (rule #18): sched_barrier(0) on BOTH sides + lgkmcnt(0)
// drain. Proven race-free (cold + L2-warm replay) in rounds 5-6.
#define HARD_BARRIER() do {                               \
    __builtin_amdgcn_sched_barrier(0);                    \
    asm volatile("s_waitcnt lgkmcnt(0)" ::: "memory");    \
    __builtin_amdgcn_s_barrier();                         \
    asm volatile("" ::: "memory");                        \
    __builtin_amdgcn_sched_barrier(0);                    \
} while (0)

__device__ __constant__ float c_nf4[16] = {
    -1.0f, -0.6961928009986877f, -0.5250730514526367f, -0.39491748809814453f,
    -0.28444138169288635f, -0.18477343022823334f, -0.09105003625154495f, 0.0f,
    0.07958029955625534f, 0.16093020141124725f, 0.24611230194568634f,
    0.33791524171829224f, 0.44070982933044434f, 0.5626170039176941f,
    0.7229568362236023f, 1.0f};

__device__ __forceinline__ unsigned bf16_rne(float f) {
    unsigned u = __float_as_uint(f);
    return (u + 0x7fffu + ((u >> 16) & 1u)) >> 16;
}

// ---------------------------------------------------------------------------
// Prep: Wc = bf16(w0 + NF4[idx]*scale + zp); xb = bf16(x)
// ---------------------------------------------------------------------------
#define W_BLOCKS ((NDIM * KDIM) / (256 * 8))   // 8192
#define X_BLOCKS ((MDIM * KDIM) / (256 * 8))   // 2048

__global__ __launch_bounds__(256) void prep_kernel(
    const float* __restrict__ x, const float* __restrict__ w0,
    const int* __restrict__ nf4_idx, const float* __restrict__ scale_p,
    const float* __restrict__ zp_p, __hip_bfloat16* __restrict__ Wc,
    __hip_bfloat16* __restrict__ xb)
{
    const int lane = threadIdx.x & 63;
    if (blockIdx.x < W_BLOCKS) {
        const float scale = scale_p[0];
        const float zp = zp_p[0];
        const int tab = __float_as_int(c_nf4[lane & 15] * scale + zp);
        const size_t base = ((size_t)blockIdx.x * 256 + threadIdx.x) * 8;
        int4v i0 = *(const int4v*)(nf4_idx + base);
        int4v i1 = *(const int4v*)(nf4_idx + base + 4);
        float4v w_0 = *(const float4v*)(w0 + base);
        float4v w_1 = *(const float4v*)(w0 + base + 4);
        unsigned r[8];
#pragma unroll
        for (int j = 0; j < 4; j++) {
            float q = __int_as_float(__builtin_amdgcn_ds_bpermute(i0[j] * 4, tab));
            r[j] = bf16_rne(w_0[j] + q);
        }
#pragma unroll
        for (int j = 0; j < 4; j++) {
            float q = __int_as_float(__builtin_amdgcn_ds_bpermute(i1[j] * 4, tab));
            r[4 + j] = bf16_rne(w_1[j] + q);
        }
        uint4v st;
        st.x = r[0] | (r[1] << 16);
        st.y = r[2] | (r[3] << 16);
        st.z = r[4] | (r[5] << 16);
        st.w = r[6] | (r[7] << 16);
        *(uint4v*)((unsigned short*)Wc + base) = st;
    } else {
        const size_t base = ((size_t)(blockIdx.x - W_BLOCKS) * 256 + threadIdx.x) * 8;
        float4v a0 = *(const float4v*)(x + base);
        float4v a1 = *(const float4v*)(x + base + 4);
        uint4v st;
        st.x = bf16_rne(a0[0]) | (bf16_rne(a0[1]) << 16);
        st.y = bf16_rne(a0[2]) | (bf16_rne(a0[3]) << 16);
        st.z = bf16_rne(a1[0]) | (bf16_rne(a1[1]) << 16);
        st.w = bf16_rne(a1[2]) | (bf16_rne(a1[3]) << 16);
        *(uint4v*)((unsigned short*)xb + base) = st;
    }
}

// ---------------------------------------------------------------------------
// GEMM: C[m][n] = sum_k A[m][k] * B[n][k]   (A,B bf16 row-major, C fp32)
// 128x128 tile, BK=128 (32 K-steps: per-step barrier/latency overhead paid
// half as often as BK=64 — round-6 lesson: overhead is per-iteration fixed).
// 8 waves (2m x 4n of 64x32), 16x16x32 MFMA; per wave-iteration 24
// ds_read_b128 feed 32 MFMAs. Double-buffered LDS (128 KB), prefetch 1,
// counted vmcnt(8) (8 loads/wave/stage). XOR chunk swizzle via pre-swizzled
// global source (LDS linear, rule #21). XCD remap: each XCD owns 4
// contiguous ntiles -> 4 MB L2-resident B panels (round-6: cut FETCH 2.7x).
// ---------------------------------------------------------------------------
__global__ __launch_bounds__(512) void gemm_kernel(
    const __hip_bfloat16* __restrict__ A,   // [MDIM][KDIM]
    const __hip_bfloat16* __restrict__ B,   // [NDIM][KDIM]
    float* __restrict__ C)                  // [MDIM][NDIM]
{
    __shared__ __hip_bfloat16 sm[2][2][BM * BK];  // 128 KiB

    const int tid = threadIdx.x;
    const int lane = tid & 63;
    const int w = tid >> 6;          // wave 0..7
    const int wr = w >> 2;           // 0..1 -> m-offset 64
    const int wc = w & 3;            // 0..3 -> n-offset 32

    // XCD remap: orig = (bid%8)*32 + bid/8 -> XCD x owns ntiles [x*4, x*4+4)
    const int bid = blockIdx.x;
    const int orig = (bid & 7) * 32 + (bid >> 3);
    const int mtile = orig & 7;      // 0..7
    const int ntile = orig >> 3;     // 0..31

    // --- staging addresses (per-lane global source, pre-swizzled) ---
    // Row = 256 B = 16 chunks of 16 B; one instr covers 4 rows (64 lanes).
    // Wave w stages rows [w*16, w*16+16) of A and of B: 4 instrs each.
    const int s_subrow = lane >> 4;          // 0..3
    const int s_chunkpos = lane & 15;        // slot within row
    int s_row[4], s_goff[4];
#pragma unroll
    for (int j = 0; j < 4; j++) {
        int row = w * 16 + j * 4 + s_subrow;
        s_row[j] = row;
        s_goff[j] = ((s_chunkpos ^ (row & 7)) ) * 8;  // content chunk for slot
    }

#define STAGE(buf, kt) do {                                                        \
    _Pragma("unroll")                                                              \
    for (int j = 0; j < 4; j++) {                                                  \
        const __hip_bfloat16* ga = A + (size_t)(mtile * BM + s_row[j]) * KDIM      \
                                     + (kt) * BK + s_goff[j];                      \
        __builtin_amdgcn_global_load_lds((const GLOBAL_AS void*)ga,                \
            (LDS_AS void*)&sm[buf][0][(w * 16 + j * 4) * BK], 16, 0, 0);           \
        const __hip_bfloat16* gb = B + (size_t)(ntile * BN + s_row[j]) * KDIM      \
                                     + (kt) * BK + s_goff[j];                      \
        __builtin_amdgcn_global_load_lds((const GLOBAL_AS void*)gb,                \
            (LDS_AS void*)&sm[buf][1][(w * 16 + j * 4) * BK], 16, 0, 0);           \
    }                                                                              \
} while (0)

    // --- fragment LDS element offsets (swizzled reads) ---
    // 16x16x32 frag at k-chunk kk (0..3): lane holds [row][kk*32+(lane>>4)*8..+8]
    int a_off[4][4], b_off[4][2];
#pragma unroll
    for (int kk = 0; kk < 4; kk++) {
#pragma unroll
        for (int m = 0; m < 4; m++) {
            int row = wr * 64 + m * 16 + (lane & 15);
            int c = kk * 4 + (lane >> 4);
            a_off[kk][m] = row * BK + (c ^ (row & 7)) * 8;
        }
#pragma unroll
        for (int n = 0; n < 2; n++) {
            int row = wc * 32 + n * 16 + (lane & 15);
            int c = kk * 4 + (lane >> 4);
            b_off[kk][n] = row * BK + (c ^ (row & 7)) * 8;
        }
    }

    f32x4 acc[4][2] = {};

#define COMPUTE(buf) do {                                                          \
    _Pragma("unroll")                                                              \
    for (int kk = 0; kk < 4; kk++) {                                               \
        short8 af[4], bfv[2];                                                      \
        _Pragma("unroll")                                                          \
        for (int m = 0; m < 4; m++)                                                \
            af[m] = *(const short8*)&sm[buf][0][a_off[kk][m]];                     \
        _Pragma("unroll")                                                          \
        for (int n = 0; n < 2; n++)                                                \
            bfv[n] = *(const short8*)&sm[buf][1][b_off[kk][n]];                    \
        _Pragma("unroll")                                                          \
        for (int m = 0; m < 4; m++)                                                \
            _Pragma("unroll")                                                      \
            for (int n = 0; n < 2; n++)                                            \
                acc[m][n] = __builtin_amdgcn_mfma_f32_16x16x32_bf16(               \
                    af[m], bfv[n], acc[m][n], 0, 0, 0);                            \
    }                                                                              \
} while (0)

    STAGE(0, 0);

    for (int t = 0; t < NT; t++) {
        const int cur = t & 1;
        // STAGE(t+1) writes buf[cur^1]; its prior readers (COMPUTE(cur^1) at
        // iter t-1) retired before the trailing barrier of t-1 (sched_barrier
        // walls prevent hoisting this above that barrier).
        if (t + 1 < NT) {
            STAGE(cur ^ 1, t + 1);
            // per-wave 8 loads/stage; stage(t+1) in flight (8) -> oldest
            // stage (t) has fully landed.
            asm volatile("s_waitcnt vmcnt(8)" ::: "memory");
        } else {
            asm volatile("s_waitcnt vmcnt(0)" ::: "memory");
        }
        HARD_BARRIER();        // all waves' stage(t) visible
        COMPUTE(cur);
        HARD_BARRIER();        // all waves done reading buf[cur] before restage
    }

    // --- epilogue: C/D layout col = lane&15, row = (lane>>4)*4 + r ---
    const int rbase = mtile * BM + wr * 64 + ((lane >> 4) << 2);
    const int cbase = ntile * BN + wc * 32 + (lane & 15);
#pragma unroll
    for (int m = 0; m < 4; m++) {
#pragma unroll
        for (int n = 0; n < 2; n++) {
#pragma unroll
            for (int r = 0; r < 4; r++) {
                C[(size_t)(rbase + m * 16 + r) * NDIM + cbase + n * 16] =
                    acc[m][n][r];
            }
        }
    }
#undef STAGE
#undef COMPUTE
}

// ---------------------------------------------------------------------------
// Fallback (only if ws too small): textbook fp32 tiled GEMM with inline dequant
// ---------------------------------------------------------------------------
__global__ void fallback_kernel(const float* __restrict__ x,
                                const float* __restrict__ w0,
                                const int* __restrict__ nf4_idx,
                                const float* __restrict__ sp,
                                const float* __restrict__ zpp,
                                float* __restrict__ out)
{
    __shared__ float As[16][16], Bs[16][17];
    const int tx = threadIdx.x, ty = threadIdx.y;
    const int n0 = blockIdx.x * 16, m0 = blockIdx.y * 16;
    const float s = sp[0], zp = zpp[0];
    float acc = 0.0f;
    for (int k0 = 0; k0 < KDIM; k0 += 16) {
        As[ty][tx] = x[(size_t)(m0 + ty) * KDIM + k0 + tx];
        int id = nf4_idx[(size_t)(n0 + ty) * KDIM + k0 + tx];
        Bs[ty][tx] = w0[(size_t)(n0 + ty) * KDIM + k0 + tx] + c_nf4[id] * s + zp;
        __syncthreads();
#pragma unroll
        for (int j = 0; j < 16; j++) acc += As[ty][j] * Bs[tx][j];
        __syncthreads();
    }
    out[(size_t)(m0 + ty) * NDIM + n0 + tx] = acc;
}

extern "C" void kernel_launch(void* const* d_in, const int* in_sizes, int n_in,
                              void* d_out, int out_size, void* d_ws, size_t ws_size,
                              hipStream_t stream) {
    const float* x = (const float*)d_in[0];
    const float* w0 = (const float*)d_in[1];
    const int* nf4_idx = (const int*)d_in[2];
    const float* scale = (const float*)d_in[3];
    const float* zp = (const float*)d_in[4];
    float* out = (float*)d_out;

    const size_t wc_bytes = (size_t)NDIM * KDIM * 2;       // 33,554,432
    const size_t xb_bytes = (size_t)MDIM * KDIM * 2;       //  8,388,608

    if (ws_size >= wc_bytes + xb_bytes) {
        __hip_bfloat16* Wc = (__hip_bfloat16*)d_ws;
        __hip_bfloat16* xb = (__hip_bfloat16*)((char*)d_ws + wc_bytes);
        prep_kernel<<<W_BLOCKS + X_BLOCKS, 256, 0, stream>>>(
            x, w0, nf4_idx, scale, zp, Wc, xb);
        gemm_kernel<<<(MDIM / BM) * (NDIM / BN), 512, 0, stream>>>(xb, Wc, out);
    } else {
        fallback_kernel<<<dim3(NDIM / 16, MDIM / 16), dim3(16, 16), 0, stream>>>(
            x, w0, nf4_idx, scale, zp, out);
    }
}

// Round 8
// 75.478 us; speedup vs baseline: 1.1059x; 1.0235x over previous
//
#include <hip/hip_runtime.h>
#include <hip/hip_bf16.h>
#include <stdint.h>

#define MDIM 1024
#define NDIM 4096
#define KDIM 4096

#define BM 128
#define BN 128
#define BK 64
#define KSPLIT 2
#define KHALF (KDIM / KSPLIT)     // 2048

typedef __attribute__((ext_vector_type(4))) float f32x4;
typedef __attribute__((ext_vector_type(4))) float float4v;
typedef __attribute__((ext_vector_type(4))) int int4v;
typedef __attribute__((ext_vector_type(4))) unsigned int uint4v;
typedef __attribute__((ext_vector_type(8))) short short8;

#define GLOBAL_AS __attribute__((address_space(1)))
#define LDS_AS __attribute__((address_space(3)))

// Hardened barrier (rule #18): sched_barrier(0) on BOTH sides + lgkmcnt(0)
// drain. Proven race-free (cold + L2-warm replay) rounds 5-7.
#define HARD_BARRIER() do {                               \
    __builtin_amdgcn_sched_barrier(0);                    \
    asm volatile("s_waitcnt lgkmcnt(0)" ::: "memory");    \
    __builtin_amdgcn_s_barrier();                         \
    asm volatile("" ::: "memory");                        \
    __builtin_amdgcn_sched_barrier(0);                    \
} while (0)

__device__ __constant__ float c_nf4[16] = {
    -1.0f, -0.6961928009986877f, -0.5250730514526367f, -0.39491748809814453f,
    -0.28444138169288635f, -0.18477343022823334f, -0.09105003625154495f, 0.0f,
    0.07958029955625534f, 0.16093020141124725f, 0.24611230194568634f,
    0.33791524171829224f, 0.44070982933044434f, 0.5626170039176941f,
    0.7229568362236023f, 1.0f};

__device__ __forceinline__ unsigned bf16_rne(float f) {
    unsigned u = __float_as_uint(f);
    return (u + 0x7fffu + ((u >> 16) & 1u)) >> 16;
}

// ---------------------------------------------------------------------------
// Prep: Wc = bf16(w0 + NF4[idx]*scale + zp); xb = bf16(x)
// ---------------------------------------------------------------------------
#define W_BLOCKS ((NDIM * KDIM) / (256 * 8))   // 8192
#define X_BLOCKS ((MDIM * KDIM) / (256 * 8))   // 2048

__global__ __launch_bounds__(256) void prep_kernel(
    const float* __restrict__ x, const float* __restrict__ w0,
    const int* __restrict__ nf4_idx, const float* __restrict__ scale_p,
    const float* __restrict__ zp_p, __hip_bfloat16* __restrict__ Wc,
    __hip_bfloat16* __restrict__ xb)
{
    const int lane = threadIdx.x & 63;
    if (blockIdx.x < W_BLOCKS) {
        const float scale = scale_p[0];
        const float zp = zp_p[0];
        const int tab = __float_as_int(c_nf4[lane & 15] * scale + zp);
        const size_t base = ((size_t)blockIdx.x * 256 + threadIdx.x) * 8;
        int4v i0 = *(const int4v*)(nf4_idx + base);
        int4v i1 = *(const int4v*)(nf4_idx + base + 4);
        float4v w_0 = *(const float4v*)(w0 + base);
        float4v w_1 = *(const float4v*)(w0 + base + 4);
        unsigned r[8];
#pragma unroll
        for (int j = 0; j < 4; j++) {
            float q = __int_as_float(__builtin_amdgcn_ds_bpermute(i0[j] * 4, tab));
            r[j] = bf16_rne(w_0[j] + q);
        }
#pragma unroll
        for (int j = 0; j < 4; j++) {
            float q = __int_as_float(__builtin_amdgcn_ds_bpermute(i1[j] * 4, tab));
            r[4 + j] = bf16_rne(w_1[j] + q);
        }
        uint4v st;
        st.x = r[0] | (r[1] << 16);
        st.y = r[2] | (r[3] << 16);
        st.z = r[4] | (r[5] << 16);
        st.w = r[6] | (r[7] << 16);
        *(uint4v*)((unsigned short*)Wc + base) = st;
    } else {
        const size_t base = ((size_t)(blockIdx.x - W_BLOCKS) * 256 + threadIdx.x) * 8;
        float4v a0 = *(const float4v*)(x + base);
        float4v a1 = *(const float4v*)(x + base + 4);
        uint4v st;
        st.x = bf16_rne(a0[0]) | (bf16_rne(a0[1]) << 16);
        st.y = bf16_rne(a0[2]) | (bf16_rne(a0[3]) << 16);
        st.z = bf16_rne(a1[0]) | (bf16_rne(a1[1]) << 16);
        st.w = bf16_rne(a1[2]) | (bf16_rne(a1[3]) << 16);
        *(uint4v*)((unsigned short*)xb + base) = st;
    }
}

// ---------------------------------------------------------------------------
// Split-K GEMM: Cp[ks][m][n] = sum_{k in half ks} A[m][k] * B[n][k]
// 128x128 tile, BK=64, 8 waves (2m x 4n of 64x32), 16x16x32 MFMA.
// Per wave-iter: 12 ds_read_b128 feed 16 MFMAs (21 FLOP/LDS-byte).
// Grid 512 = 2 blocks/CU (64 KB LDS dbuf) -> cross-block stall overlap,
// the co-residency rounds 2-7 never had with the 128^2 tile.
// Counted vmcnt(4) (4 loads/wave/stage, prefetch 1). XOR chunk swizzle via
// pre-swizzled global source (LDS linear, rule #21). XCD remap: each XCD
// owns 4 contiguous ntiles (both K-halves) -> 4 MB L2-resident Wc panels.
// ---------------------------------------------------------------------------
__global__ __launch_bounds__(512, 4) void gemm_splitk(
    const __hip_bfloat16* __restrict__ A,   // [MDIM][KDIM]
    const __hip_bfloat16* __restrict__ B,   // [NDIM][KDIM]
    float* __restrict__ Cp)                 // [KSPLIT][MDIM][NDIM]
{
    __shared__ __hip_bfloat16 sm[2][2][BM * BK];  // 64 KiB

    const int tid = threadIdx.x;
    const int lane = tid & 63;
    const int w = tid >> 6;          // wave 0..7
    const int wr = w >> 2;           // 0..1 -> m-offset 64
    const int wc = w & 3;            // 0..3 -> n-offset 32

    // XCD remap: orig = (bid%8)*64 + bid/8; tile = orig>>1, ks = orig&1.
    // XCD x owns tiles [x*32..+32) -> ntiles [x*4, x*4+4) (both K-halves).
    const int bid = blockIdx.x;
    const int orig = (bid & 7) * 64 + (bid >> 3);
    const int ks = orig & 1;
    const int tile = orig >> 1;
    const int mtile = tile & 7;      // 0..7
    const int ntile = tile >> 3;     // 0..31
    const int kbase = ks * KHALF;

    // --- staging addresses (per-lane global source, pre-swizzled) ---
    // wave w stages rows [w*16, w*16+16) of A-tile and of B-tile: 2 instrs
    // each (8 rows / instr; lane -> row = base + lane/8, chunk slot = lane%8)
    const int s_subrow = lane >> 3;
    const int s_chunkpos = lane & 7;
    int s_row[2], s_goff[2];
#pragma unroll
    for (int j = 0; j < 2; j++) {
        int row = w * 16 + j * 8 + s_subrow;
        s_row[j] = row;
        s_goff[j] = (s_chunkpos ^ (row & 7)) * 8;
    }

#define STAGE(buf, kt) do {                                                        \
    _Pragma("unroll")                                                              \
    for (int j = 0; j < 2; j++) {                                                  \
        const __hip_bfloat16* ga = A + (size_t)(mtile * BM + s_row[j]) * KDIM      \
                                     + kbase + (kt) * BK + s_goff[j];              \
        __builtin_amdgcn_global_load_lds((const GLOBAL_AS void*)ga,                \
            (LDS_AS void*)&sm[buf][0][(w * 16 + j * 8) * BK], 16, 0, 0);           \
        const __hip_bfloat16* gb = B + (size_t)(ntile * BN + s_row[j]) * KDIM      \
                                     + kbase + (kt) * BK + s_goff[j];              \
        __builtin_amdgcn_global_load_lds((const GLOBAL_AS void*)gb,                \
            (LDS_AS void*)&sm[buf][1][(w * 16 + j * 8) * BK], 16, 0, 0);           \
    }                                                                              \
} while (0)

    // --- fragment LDS element offsets (swizzled reads) ---
    int a_off[2][4], b_off[2][2];
#pragma unroll
    for (int kk2 = 0; kk2 < 2; kk2++) {
#pragma unroll
        for (int m = 0; m < 4; m++) {
            int row = wr * 64 + m * 16 + (lane & 15);
            int ch = (kk2 * 4 + (lane >> 4)) ^ (row & 7);
            a_off[kk2][m] = row * BK + ch * 8;
        }
#pragma unroll
        for (int n = 0; n < 2; n++) {
            int row = wc * 32 + n * 16 + (lane & 15);
            int ch = (kk2 * 4 + (lane >> 4)) ^ (row & 7);
            b_off[kk2][n] = row * BK + ch * 8;
        }
    }

    f32x4 acc[4][2] = {};

#define COMPUTE(buf) do {                                                          \
    _Pragma("unroll")                                                              \
    for (int kk2 = 0; kk2 < 2; kk2++) {                                            \
        short8 af[4], bfv[2];                                                      \
        _Pragma("unroll")                                                          \
        for (int m = 0; m < 4; m++)                                                \
            af[m] = *(const short8*)&sm[buf][0][a_off[kk2][m]];                    \
        _Pragma("unroll")                                                          \
        for (int n = 0; n < 2; n++)                                                \
            bfv[n] = *(const short8*)&sm[buf][1][b_off[kk2][n]];                   \
        _Pragma("unroll")                                                          \
        for (int m = 0; m < 4; m++)                                                \
            _Pragma("unroll")                                                      \
            for (int n = 0; n < 2; n++)                                            \
                acc[m][n] = __builtin_amdgcn_mfma_f32_16x16x32_bf16(               \
                    af[m], bfv[n], acc[m][n], 0, 0, 0);                            \
    }                                                                              \
} while (0)

    const int NT = KHALF / BK;   // 32
    STAGE(0, 0);

    for (int t = 0; t < NT; t++) {
        const int cur = t & 1;
        if (t + 1 < NT) {
            STAGE(cur ^ 1, t + 1);
            // per-wave 4 loads/stage; stage(t+1) in flight -> vmcnt(4)
            // means stage(t) fully landed.
            asm volatile("s_waitcnt vmcnt(4)" ::: "memory");
        } else {
            asm volatile("s_waitcnt vmcnt(0)" ::: "memory");
        }
        HARD_BARRIER();        // all waves' stage(t) visible
        COMPUTE(cur);
        HARD_BARRIER();        // all waves done reading buf[cur] before restage
    }

    // --- epilogue: C/D layout col = lane&15, row = (lane>>4)*4 + r ---
    float* Cout = Cp + (size_t)ks * MDIM * NDIM;
    const int rbase = mtile * BM + wr * 64 + ((lane >> 4) << 2);
    const int cbase = ntile * BN + wc * 32 + (lane & 15);
#pragma unroll
    for (int m = 0; m < 4; m++) {
#pragma unroll
        for (int n = 0; n < 2; n++) {
#pragma unroll
            for (int r = 0; r < 4; r++) {
                Cout[(size_t)(rbase + m * 16 + r) * NDIM + cbase + n * 16] =
                    acc[m][n][r];
            }
        }
    }
#undef STAGE
#undef COMPUTE
}

// ---------------------------------------------------------------------------
// Reduce: C = Cp[0] + Cp[1]   (float4 per thread, deterministic)
// ---------------------------------------------------------------------------
#define R_BLOCKS ((MDIM * NDIM) / (256 * 4))   // 4096

__global__ __launch_bounds__(256) void reduce_kernel(
    const float* __restrict__ Cp, float* __restrict__ C)
{
    const size_t base = ((size_t)blockIdx.x * 256 + threadIdx.x) * 4;
    float4v a = *(const float4v*)(Cp + base);
    float4v b = *(const float4v*)(Cp + (size_t)MDIM * NDIM + base);
    *(float4v*)(C + base) = a + b;
}

// ---------------------------------------------------------------------------
// Single-K GEMM (round-3 proven config) — used when ws can't hold Cp.
// ---------------------------------------------------------------------------
__global__ __launch_bounds__(512) void gemm_single(
    const __hip_bfloat16* __restrict__ A,
    const __hip_bfloat16* __restrict__ B,
    float* __restrict__ C)
{
    __shared__ __hip_bfloat16 sm[3][2][BM * BK];  // 96 KiB

    const int tid = threadIdx.x;
    const int lane = tid & 63;
    const int w = tid >> 6;
    const int wr = w >> 2;
    const int wc = w & 3;

    const int bid = blockIdx.x;
    const int orig = (bid & 7) * 32 + (bid >> 3);
    const int mtile = orig & 7;
    const int ntile = orig >> 3;

    const int s_subrow = lane >> 3;
    const int s_chunkpos = lane & 7;
    int s_row[2], s_goff[2];
#pragma unroll
    for (int j = 0; j < 2; j++) {
        int row = w * 16 + j * 8 + s_subrow;
        s_row[j] = row;
        s_goff[j] = (s_chunkpos ^ (row & 7)) * 8;
    }

#define STAGE(buf, kt) do {                                                        \
    _Pragma("unroll")                                                              \
    for (int j = 0; j < 2; j++) {                                                  \
        const __hip_bfloat16* ga = A + (size_t)(mtile * BM + s_row[j]) * KDIM      \
                                     + (kt) * BK + s_goff[j];                      \
        __builtin_amdgcn_global_load_lds((const GLOBAL_AS void*)ga,                \
            (LDS_AS void*)&sm[buf][0][(w * 16 + j * 8) * BK], 16, 0, 0);           \
        const __hip_bfloat16* gb = B + (size_t)(ntile * BN + s_row[j]) * KDIM      \
                                     + (kt) * BK + s_goff[j];                      \
        __builtin_amdgcn_global_load_lds((const GLOBAL_AS void*)gb,                \
            (LDS_AS void*)&sm[buf][1][(w * 16 + j * 8) * BK], 16, 0, 0);           \
    }                                                                              \
} while (0)

    int a_off[2][4], b_off[2][2];
#pragma unroll
    for (int kk2 = 0; kk2 < 2; kk2++) {
#pragma unroll
        for (int m = 0; m < 4; m++) {
            int row = wr * 64 + m * 16 + (lane & 15);
            int ch = (kk2 * 4 + (lane >> 4)) ^ (row & 7);
            a_off[kk2][m] = row * BK + ch * 8;
        }
#pragma unroll
        for (int n = 0; n < 2; n++) {
            int row = wc * 32 + n * 16 + (lane & 15);
            int ch = (kk2 * 4 + (lane >> 4)) ^ (row & 7);
            b_off[kk2][n] = row * BK + ch * 8;
        }
    }

    f32x4 acc[4][2] = {};

#define COMPUTE(buf) do {                                                          \
    _Pragma("unroll")                                                              \
    for (int kk2 = 0; kk2 < 2; kk2++) {                                            \
        short8 af[4], bfv[2];                                                      \
        _Pragma("unroll")                                                          \
        for (int m = 0; m < 4; m++)                                                \
            af[m] = *(const short8*)&sm[buf][0][a_off[kk2][m]];                    \
        _Pragma("unroll")                                                          \
        for (int n = 0; n < 2; n++)                                                \
            bfv[n] = *(const short8*)&sm[buf][1][b_off[kk2][n]];                   \
        _Pragma("unroll")                                                          \
        for (int m = 0; m < 4; m++)                                                \
            _Pragma("unroll")                                                      \
            for (int n = 0; n < 2; n++)                                            \
                acc[m][n] = __builtin_amdgcn_mfma_f32_16x16x32_bf16(               \
                    af[m], bfv[n], acc[m][n], 0, 0, 0);                            \
    }                                                                              \
} while (0)

    const int NT = KDIM / BK;  // 64
    STAGE(0, 0);
    STAGE(1, 1);

    for (int t = 0; t < NT; t++) {
        const int cur = t % 3;
        if (t + 2 < NT) {
            STAGE((t + 2) % 3, t + 2);
            asm volatile("s_waitcnt vmcnt(8)" ::: "memory");
        } else if (t + 1 < NT) {
            asm volatile("s_waitcnt vmcnt(4)" ::: "memory");
        } else {
            asm volatile("s_waitcnt vmcnt(0)" ::: "memory");
        }
        HARD_BARRIER();
        COMPUTE(cur);
        HARD_BARRIER();
    }

    const int rbase = mtile * BM + wr * 64 + ((lane >> 4) << 2);
    const int cbase = ntile * BN + wc * 32 + (lane & 15);
#pragma unroll
    for (int m = 0; m < 4; m++) {
#pragma unroll
        for (int n = 0; n < 2; n++) {
#pragma unroll
            for (int r = 0; r < 4; r++) {
                C[(size_t)(rbase + m * 16 + r) * NDIM + cbase + n * 16] =
                    acc[m][n][r];
            }
        }
    }
#undef STAGE
#undef COMPUTE
}

// ---------------------------------------------------------------------------
// Fallback (ws too small even for Wc+xb): textbook fp32 tiled GEMM
// ---------------------------------------------------------------------------
__global__ void fallback_kernel(const float* __restrict__ x,
                                const float* __restrict__ w0,
                                const int* __restrict__ nf4_idx,
                                const float* __restrict__ sp,
                                const float* __restrict__ zpp,
                                float* __restrict__ out)
{
    __shared__ float As[16][16], Bs[16][17];
    const int tx = threadIdx.x, ty = threadIdx.y;
    const int n0 = blockIdx.x * 16, m0 = blockIdx.y * 16;
    const float s = sp[0], zp = zpp[0];
    float acc = 0.0f;
    for (int k0 = 0; k0 < KDIM; k0 += 16) {
        As[ty][tx] = x[(size_t)(m0 + ty) * KDIM + k0 + tx];
        int id = nf4_idx[(size_t)(n0 + ty) * KDIM + k0 + tx];
        Bs[ty][tx] = w0[(size_t)(n0 + ty) * KDIM + k0 + tx] + c_nf4[id] * s + zp;
        __syncthreads();
#pragma unroll
        for (int j = 0; j < 16; j++) acc += As[ty][j] * Bs[tx][j];
        __syncthreads();
    }
    out[(size_t)(m0 + ty) * NDIM + n0 + tx] = acc;
}

extern "C" void kernel_launch(void* const* d_in, const int* in_sizes, int n_in,
                              void* d_out, int out_size, void* d_ws, size_t ws_size,
                              hipStream_t stream) {
    const float* x = (const float*)d_in[0];
    const float* w0 = (const float*)d_in[1];
    const int* nf4_idx = (const int*)d_in[2];
    const float* scale = (const float*)d_in[3];
    const float* zp = (const float*)d_in[4];
    float* out = (float*)d_out;

    const size_t wc_bytes = (size_t)NDIM * KDIM * 2;           // 33,554,432
    const size_t xb_bytes = (size_t)MDIM * KDIM * 2;           //  8,388,608
    const size_t cp_bytes = (size_t)KSPLIT * MDIM * NDIM * 4;  // 33,554,432

    if (ws_size >= wc_bytes + xb_bytes + cp_bytes) {
        __hip_bfloat16* Wc = (__hip_bfloat16*)d_ws;
        __hip_bfloat16* xb = (__hip_bfloat16*)((char*)d_ws + wc_bytes);
        float* Cp = (float*)((char*)d_ws + wc_bytes + xb_bytes);
        prep_kernel<<<W_BLOCKS + X_BLOCKS, 256, 0, stream>>>(
            x, w0, nf4_idx, scale, zp, Wc, xb);
        gemm_splitk<<<(MDIM / BM) * (NDIM / BN) * KSPLIT, 512, 0, stream>>>(
            xb, Wc, Cp);
        reduce_kernel<<<R_BLOCKS, 256, 0, stream>>>(Cp, out);
    } else if (ws_size >= wc_bytes + xb_bytes) {
        __hip_bfloat16* Wc = (__hip_bfloat16*)d_ws;
        __hip_bfloat16* xb = (__hip_bfloat16*)((char*)d_ws + wc_bytes);
        prep_kernel<<<W_BLOCKS + X_BLOCKS, 256, 0, stream>>>(
            x, w0, nf4_idx, scale, zp, Wc, xb);
        gemm_single<<<(MDIM / BM) * (NDIM / BN), 512, 0, stream>>>(xb, Wc, out);
    } else {
        fallback_kernel<<<dim3(NDIM / 16, MDIM / 16), dim3(16, 16), 0, stream>>>(
            x, w0, nf4_idx, scale, zp, out);
    }
}

// Round 9
// 67.288 us; speedup vs baseline: 1.2405x; 1.1217x over previous
//
#include <hip/hip_runtime.h>
#include <hip/hip_bf16.h>
#include <stdint.h>

#define MDIM 1024
#define NDIM 4096
#define KDIM 4096

#define BM 128
#define BN 128
#define BK 64

typedef __attribute__((ext_vector_type(4))) float f32x4;
typedef __attribute__((ext_vector_type(4))) float float4v;
typedef __attribute__((ext_vector_type(4))) int int4v;
typedef __attribute__((ext_vector_type(4))) unsigned int uint4v;
typedef __attribute__((ext_vector_type(8))) short short8;

#define GLOBAL_AS __attribute__((address_space(1)))
#define LDS_AS __attribute__((address_space(3)))

// Hardened barrier (rule #18): sched_barrier(0) on BOTH sides + lgkmcnt(0)
// drain. Race-free across rounds 5-8 benches (cold + L2-warm replay).
// Now paid ONCE per K-step (the lgkmcnt drain is ~free there: all ds_reads
// were already consumed by MFMAs).
#define HARD_BARRIER() do {                               \
    __builtin_amdgcn_sched_barrier(0);                    \
    asm volatile("s_waitcnt lgkmcnt(0)" ::: "memory");    \
    __builtin_amdgcn_s_barrier();                         \
    asm volatile("" ::: "memory");                        \
    __builtin_amdgcn_sched_barrier(0);                    \
} while (0)

__device__ __constant__ float c_nf4[16] = {
    -1.0f, -0.6961928009986877f, -0.5250730514526367f, -0.39491748809814453f,
    -0.28444138169288635f, -0.18477343022823334f, -0.09105003625154495f, 0.0f,
    0.07958029955625534f, 0.16093020141124725f, 0.24611230194568634f,
    0.33791524171829224f, 0.44070982933044434f, 0.5626170039176941f,
    0.7229568362236023f, 1.0f};

__device__ __forceinline__ unsigned bf16_rne(float f) {
    unsigned u = __float_as_uint(f);
    return (u + 0x7fffu + ((u >> 16) & 1u)) >> 16;
}

// ---------------------------------------------------------------------------
// Prep: Wc = bf16(w0 + NF4[idx]*scale + zp); xb = bf16(x)
// ---------------------------------------------------------------------------
#define W_BLOCKS ((NDIM * KDIM) / (256 * 8))   // 8192
#define X_BLOCKS ((MDIM * KDIM) / (256 * 8))   // 2048

__global__ __launch_bounds__(256) void prep_kernel(
    const float* __restrict__ x, const float* __restrict__ w0,
    const int* __restrict__ nf4_idx, const float* __restrict__ scale_p,
    const float* __restrict__ zp_p, __hip_bfloat16* __restrict__ Wc,
    __hip_bfloat16* __restrict__ xb)
{
    const int lane = threadIdx.x & 63;
    if (blockIdx.x < W_BLOCKS) {
        const float scale = scale_p[0];
        const float zp = zp_p[0];
        const int tab = __float_as_int(c_nf4[lane & 15] * scale + zp);
        const size_t base = ((size_t)blockIdx.x * 256 + threadIdx.x) * 8;
        int4v i0 = *(const int4v*)(nf4_idx + base);
        int4v i1 = *(const int4v*)(nf4_idx + base + 4);
        float4v w_0 = *(const float4v*)(w0 + base);
        float4v w_1 = *(const float4v*)(w0 + base + 4);
        unsigned r[8];
#pragma unroll
        for (int j = 0; j < 4; j++) {
            float q = __int_as_float(__builtin_amdgcn_ds_bpermute(i0[j] * 4, tab));
            r[j] = bf16_rne(w_0[j] + q);
        }
#pragma unroll
        for (int j = 0; j < 4; j++) {
            float q = __int_as_float(__builtin_amdgcn_ds_bpermute(i1[j] * 4, tab));
            r[4 + j] = bf16_rne(w_1[j] + q);
        }
        uint4v st;
        st.x = r[0] | (r[1] << 16);
        st.y = r[2] | (r[3] << 16);
        st.z = r[4] | (r[5] << 16);
        st.w = r[6] | (r[7] << 16);
        *(uint4v*)((unsigned short*)Wc + base) = st;
    } else {
        const size_t base = ((size_t)(blockIdx.x - W_BLOCKS) * 256 + threadIdx.x) * 8;
        float4v a0 = *(const float4v*)(x + base);
        float4v a1 = *(const float4v*)(x + base + 4);
        uint4v st;
        st.x = bf16_rne(a0[0]) | (bf16_rne(a0[1]) << 16);
        st.y = bf16_rne(a0[2]) | (bf16_rne(a0[3]) << 16);
        st.z = bf16_rne(a1[0]) | (bf16_rne(a1[1]) << 16);
        st.w = bf16_rne(a1[2]) | (bf16_rne(a1[3]) << 16);
        *(uint4v*)((unsigned short*)xb + base) = st;
    }
}

// ---------------------------------------------------------------------------
// GEMM: C[m][n] = sum_k A[m][k] * B[n][k]   (A,B bf16 row-major, C fp32)
// Round-3 proven shell (128x128 tile, BK=64, 8 waves 2m x 4n of 64x32,
// 16x16x32 MFMA, pf distance 2, counted vmcnt(8), XOR swizzle via
// pre-swizzled global source, XCD remap) with ONE barrier per K-step:
// 4 LDS buffers (128 KB) give WAR distance >= 2 mod 4 for all concurrent
// reader/writer pairs, so the trailing (WAR) barrier is deleted.
// Hazard algebra: STAGE(t+2)->(t+2)%4; concurrent readers are at (t-1)%4
// (waves still in COMPUTE(t-1)) and t%4 (after barrier) -> distances 3,2.
// A one-barrier compiler hoist adds reader (t-2)%4 -> distance 4... = 0?
// No: hoist above barrier(t) is where STAGE already sits; hoisting above
// barrier(t-1) is blocked by the memory-clobber fences + sched_barrier(0).
// ---------------------------------------------------------------------------
__global__ __launch_bounds__(512) void gemm_kernel(
    const __hip_bfloat16* __restrict__ A,   // [MDIM][KDIM]
    const __hip_bfloat16* __restrict__ B,   // [NDIM][KDIM]
    float* __restrict__ C)                  // [MDIM][NDIM]
{
    __shared__ __hip_bfloat16 sm[4][2][BM * BK];  // 128 KiB

    const int tid = threadIdx.x;
    const int lane = tid & 63;
    const int w = tid >> 6;          // wave 0..7
    const int wr = w >> 2;           // 0..1 -> m-offset 64
    const int wc = w & 3;            // 0..3 -> n-offset 32

    // XCD remap: orig = (bid%8)*32 + bid/8 -> XCD x owns ntiles [x*4, x*4+4)
    // (round 6: cut FETCH 2.7x via L2-resident B panels)
    const int bid = blockIdx.x;
    const int orig = (bid & 7) * 32 + (bid >> 3);
    const int mtile = orig & 7;      // 0..7
    const int ntile = orig >> 3;     // 0..31

    // --- staging addresses (per-lane global source, pre-swizzled) ---
    // wave w stages rows [w*16, w*16+16) of A-tile and of B-tile: 2 instrs
    // each (8 rows / instr; lane -> row = base + lane/8, chunk slot = lane%8)
    const int s_subrow = lane >> 3;
    const int s_chunkpos = lane & 7;
    int s_row[2], s_goff[2];
#pragma unroll
    for (int j = 0; j < 2; j++) {
        int row = w * 16 + j * 8 + s_subrow;
        s_row[j] = row;
        s_goff[j] = (s_chunkpos ^ (row & 7)) * 8;  // content chunk for slot
    }

#define STAGE(buf, kt) do {                                                        \
    _Pragma("unroll")                                                              \
    for (int j = 0; j < 2; j++) {                                                  \
        const __hip_bfloat16* ga = A + (size_t)(mtile * BM + s_row[j]) * KDIM      \
                                     + (kt) * BK + s_goff[j];                      \
        __builtin_amdgcn_global_load_lds((const GLOBAL_AS void*)ga,                \
            (LDS_AS void*)&sm[buf][0][(w * 16 + j * 8) * BK], 16, 0, 0);           \
        const __hip_bfloat16* gb = B + (size_t)(ntile * BN + s_row[j]) * KDIM      \
                                     + (kt) * BK + s_goff[j];                      \
        __builtin_amdgcn_global_load_lds((const GLOBAL_AS void*)gb,                \
            (LDS_AS void*)&sm[buf][1][(w * 16 + j * 8) * BK], 16, 0, 0);           \
    }                                                                              \
} while (0)

    // --- fragment LDS element offsets (swizzled reads) ---
    int a_off[2][4], b_off[2][2];
#pragma unroll
    for (int kk2 = 0; kk2 < 2; kk2++) {
#pragma unroll
        for (int m = 0; m < 4; m++) {
            int row = wr * 64 + m * 16 + (lane & 15);
            int ch = (kk2 * 4 + (lane >> 4)) ^ (row & 7);
            a_off[kk2][m] = row * BK + ch * 8;
        }
#pragma unroll
        for (int n = 0; n < 2; n++) {
            int row = wc * 32 + n * 16 + (lane & 15);
            int ch = (kk2 * 4 + (lane >> 4)) ^ (row & 7);
            b_off[kk2][n] = row * BK + ch * 8;
        }
    }

    f32x4 acc[4][2] = {};

#define COMPUTE(buf) do {                                                          \
    _Pragma("unroll")                                                              \
    for (int kk2 = 0; kk2 < 2; kk2++) {                                            \
        short8 af[4], bfv[2];                                                      \
        _Pragma("unroll")                                                          \
        for (int m = 0; m < 4; m++)                                                \
            af[m] = *(const short8*)&sm[buf][0][a_off[kk2][m]];                    \
        _Pragma("unroll")                                                          \
        for (int n = 0; n < 2; n++)                                                \
            bfv[n] = *(const short8*)&sm[buf][1][b_off[kk2][n]];                   \
        _Pragma("unroll")                                                          \
        for (int m = 0; m < 4; m++)                                                \
            _Pragma("unroll")                                                      \
            for (int n = 0; n < 2; n++)                                            \
                acc[m][n] = __builtin_amdgcn_mfma_f32_16x16x32_bf16(               \
                    af[m], bfv[n], acc[m][n], 0, 0, 0);                            \
    }                                                                              \
} while (0)

    const int NT = KDIM / BK;  // 64 (NT % 4 == 0)
    STAGE(0, 0);
    STAGE(1, 1);

    for (int t = 0; t < NT; t++) {
        const int cur = t & 3;
        if (t + 2 < NT) {
            STAGE((t + 2) & 3, t + 2);
            // per-wave 4 loads/stage; stages t+1,t+2 in flight (8) ->
            // oldest stage (t) has landed (wave-locally).
            asm volatile("s_waitcnt vmcnt(8)" ::: "memory");
        } else if (t + 1 < NT) {
            asm volatile("s_waitcnt vmcnt(4)" ::: "memory");
        } else {
            asm volatile("s_waitcnt vmcnt(0)" ::: "memory");
        }
        HARD_BARRIER();        // single barrier: every wave's stage(t) landed
        COMPUTE(cur);          // WAR protection for restage = buffer distance
    }

    // --- epilogue: C/D layout col = lane&15, row = (lane>>4)*4 + r ---
    const int rbase = mtile * BM + wr * 64 + ((lane >> 4) << 2);
    const int cbase = ntile * BN + wc * 32 + (lane & 15);
#pragma unroll
    for (int m = 0; m < 4; m++) {
#pragma unroll
        for (int n = 0; n < 2; n++) {
#pragma unroll
            for (int r = 0; r < 4; r++) {
                C[(size_t)(rbase + m * 16 + r) * NDIM + cbase + n * 16] =
                    acc[m][n][r];
            }
        }
    }
#undef STAGE
#undef COMPUTE
}

// ---------------------------------------------------------------------------
// Fallback (only if ws too small): textbook fp32 tiled GEMM with inline dequant
// ---------------------------------------------------------------------------
__global__ void fallback_kernel(const float* __restrict__ x,
                                const float* __restrict__ w0,
                                const int* __restrict__ nf4_idx,
                                const float* __restrict__ sp,
                                const float* __restrict__ zpp,
                                float* __restrict__ out)
{
    __shared__ float As[16][16], Bs[16][17];
    const int tx = threadIdx.x, ty = threadIdx.y;
    const int n0 = blockIdx.x * 16, m0 = blockIdx.y * 16;
    const float s = sp[0], zp = zpp[0];
    float acc = 0.0f;
    for (int k0 = 0; k0 < KDIM; k0 += 16) {
        As[ty][tx] = x[(size_t)(m0 + ty) * KDIM + k0 + tx];
        int id = nf4_idx[(size_t)(n0 + ty) * KDIM + k0 + tx];
        Bs[ty][tx] = w0[(size_t)(n0 + ty) * KDIM + k0 + tx] + c_nf4[id] * s + zp;
        __syncthreads();
#pragma unroll
        for (int j = 0; j < 16; j++) acc += As[ty][j] * Bs[tx][j];
        __syncthreads();
    }
    out[(size_t)(m0 + ty) * NDIM + n0 + tx] = acc;
}

extern "C" void kernel_launch(void* const* d_in, const int* in_sizes, int n_in,
                              void* d_out, int out_size, void* d_ws, size_t ws_size,
                              hipStream_t stream) {
    const float* x = (const float*)d_in[0];
    const float* w0 = (const float*)d_in[1];
    const int* nf4_idx = (const int*)d_in[2];
    const float* scale = (const float*)d_in[3];
    const float* zp = (const float*)d_in[4];
    float* out = (float*)d_out;

    const size_t wc_bytes = (size_t)NDIM * KDIM * 2;       // 33,554,432
    const size_t xb_bytes = (size_t)MDIM * KDIM * 2;       //  8,388,608

    if (ws_size >= wc_bytes + xb_bytes) {
        __hip_bfloat16* Wc = (__hip_bfloat16*)d_ws;
        __hip_bfloat16* xb = (__hip_bfloat16*)((char*)d_ws + wc_bytes);
        prep_kernel<<<W_BLOCKS + X_BLOCKS, 256, 0, stream>>>(
            x, w0, nf4_idx, scale, zp, Wc, xb);
        gemm_kernel<<<(MDIM / BM) * (NDIM / BN), 512, 0, stream>>>(xb, Wc, out);
    } else {
        fallback_kernel<<<dim3(NDIM / 16, MDIM / 16), dim3(16, 16), 0, stream>>>(
            x, w0, nf4_idx, scale, zp, out);
    }
}

// Round 10
// 66.568 us; speedup vs baseline: 1.2540x; 1.0108x over previous
//
#include <hip/hip_runtime.h>
#include <hip/hip_bf16.h>
#include <stdint.h>

#define MDIM 1024
#define NDIM 4096
#define KDIM 4096

#define BM 128
#define BN 128
#define BK 64

typedef __attribute__((ext_vector_type(4))) float f32x4;
typedef __attribute__((ext_vector_type(4))) float float4v;
typedef __attribute__((ext_vector_type(4))) int int4v;
typedef __attribute__((ext_vector_type(4))) unsigned int uint4v;
typedef __attribute__((ext_vector_type(8))) short short8;

#define GLOBAL_AS __attribute__((address_space(1)))
#define LDS_AS __attribute__((address_space(3)))

// Hardened barrier (rule #18): sched_barrier(0) on BOTH sides + lgkmcnt(0)
// drain. Race-free across rounds 5-9 benches (cold + L2-warm replay).
#define HARD_BARRIER() do {                               \
    __builtin_amdgcn_sched_barrier(0);                    \
    asm volatile("s_waitcnt lgkmcnt(0)" ::: "memory");    \
    __builtin_amdgcn_s_barrier();                         \
    asm volatile("" ::: "memory");                        \
    __builtin_amdgcn_sched_barrier(0);                    \
} while (0)

__device__ __constant__ float c_nf4[16] = {
    -1.0f, -0.6961928009986877f, -0.5250730514526367f, -0.39491748809814453f,
    -0.28444138169288635f, -0.18477343022823334f, -0.09105003625154495f, 0.0f,
    0.07958029955625534f, 0.16093020141124725f, 0.24611230194568634f,
    0.33791524171829224f, 0.44070982933044434f, 0.5626170039176941f,
    0.7229568362236023f, 1.0f};

__device__ __forceinline__ unsigned bf16_rne(float f) {
    unsigned u = __float_as_uint(f);
    return (u + 0x7fffu + ((u >> 16) & 1u)) >> 16;
}

// ---------------------------------------------------------------------------
// Prep: Wc = bf16(w0 + NF4[idx]*scale + zp); xb = bf16(x)
// ---------------------------------------------------------------------------
#define W_BLOCKS ((NDIM * KDIM) / (256 * 8))   // 8192
#define X_BLOCKS ((MDIM * KDIM) / (256 * 8))   // 2048

__global__ __launch_bounds__(256) void prep_kernel(
    const float* __restrict__ x, const float* __restrict__ w0,
    const int* __restrict__ nf4_idx, const float* __restrict__ scale_p,
    const float* __restrict__ zp_p, __hip_bfloat16* __restrict__ Wc,
    __hip_bfloat16* __restrict__ xb)
{
    const int lane = threadIdx.x & 63;
    if (blockIdx.x < W_BLOCKS) {
        const float scale = scale_p[0];
        const float zp = zp_p[0];
        const int tab = __float_as_int(c_nf4[lane & 15] * scale + zp);
        const size_t base = ((size_t)blockIdx.x * 256 + threadIdx.x) * 8;
        int4v i0 = *(const int4v*)(nf4_idx + base);
        int4v i1 = *(const int4v*)(nf4_idx + base + 4);
        float4v w_0 = *(const float4v*)(w0 + base);
        float4v w_1 = *(const float4v*)(w0 + base + 4);
        unsigned r[8];
#pragma unroll
        for (int j = 0; j < 4; j++) {
            float q = __int_as_float(__builtin_amdgcn_ds_bpermute(i0[j] * 4, tab));
            r[j] = bf16_rne(w_0[j] + q);
        }
#pragma unroll
        for (int j = 0; j < 4; j++) {
            float q = __int_as_float(__builtin_amdgcn_ds_bpermute(i1[j] * 4, tab));
            r[4 + j] = bf16_rne(w_1[j] + q);
        }
        uint4v st;
        st.x = r[0] | (r[1] << 16);
        st.y = r[2] | (r[3] << 16);
        st.z = r[4] | (r[5] << 16);
        st.w = r[6] | (r[7] << 16);
        *(uint4v*)((unsigned short*)Wc + base) = st;
    } else {
        const size_t base = ((size_t)(blockIdx.x - W_BLOCKS) * 256 + threadIdx.x) * 8;
        float4v a0 = *(const float4v*)(x + base);
        float4v a1 = *(const float4v*)(x + base + 4);
        uint4v st;
        st.x = bf16_rne(a0[0]) | (bf16_rne(a0[1]) << 16);
        st.y = bf16_rne(a0[2]) | (bf16_rne(a0[3]) << 16);
        st.z = bf16_rne(a1[0]) | (bf16_rne(a1[1]) << 16);
        st.w = bf16_rne(a1[2]) | (bf16_rne(a1[3]) << 16);
        *(uint4v*)((unsigned short*)xb + base) = st;
    }
}

// ---------------------------------------------------------------------------
// GEMM: C[m][n] = sum_k A[m][k] * B[n][k]   (A,B bf16 row-major, C fp32)
// Round-9 shell (128x128 tile, BK=64, 4 LDS buffers, ONE barrier/K-step,
// pf distance 2, counted vmcnt(8), XOR swizzle via pre-swizzled global
// source, XCD remap) + LDS-minimal wave split 2m x 2n x 2k:
// each wave computes a 64x64 output over HALF of each BK step, so A and B
// are each read only 2x redundantly -> 64 KB LDS reads/K-step (was 96 KB
// with 2m x 4n; LDS pipe was ~73% of the iteration at 85 B/cy).
// Cross-wk pairs reduce through LDS after the loop (round-5-proven),
// guarded by an explicit post-loop barrier (1-barrier loop has no trailing
// sync).
// ---------------------------------------------------------------------------
__global__ __launch_bounds__(512) void gemm_kernel(
    const __hip_bfloat16* __restrict__ A,   // [MDIM][KDIM]
    const __hip_bfloat16* __restrict__ B,   // [NDIM][KDIM]
    float* __restrict__ C)                  // [MDIM][NDIM]
{
    __shared__ __hip_bfloat16 sm[4][2][BM * BK];  // 128 KiB

    const int tid = threadIdx.x;
    const int lane = tid & 63;
    const int w = tid >> 6;          // wave 0..7
    const int wr = w >> 2;           // 0..1 -> m-offset 64
    const int wc = (w >> 1) & 1;     // 0..1 -> n-offset 64
    const int wk = w & 1;            // 0..1 -> k-half within BK

    // XCD remap: orig = (bid%8)*32 + bid/8 -> XCD x owns ntiles [x*4, x*4+4)
    const int bid = blockIdx.x;
    const int orig = (bid & 7) * 32 + (bid >> 3);
    const int mtile = orig & 7;      // 0..7
    const int ntile = orig >> 3;     // 0..31

    // --- staging addresses (per-lane global source, pre-swizzled) ---
    // wave w stages rows [w*16, w*16+16) of A-tile and of B-tile: 2 instrs
    // each (8 rows / instr; lane -> row = base + lane/8, chunk slot = lane%8)
    const int s_subrow = lane >> 3;
    const int s_chunkpos = lane & 7;
    int s_row[2], s_goff[2];
#pragma unroll
    for (int j = 0; j < 2; j++) {
        int row = w * 16 + j * 8 + s_subrow;
        s_row[j] = row;
        s_goff[j] = (s_chunkpos ^ (row & 7)) * 8;  // content chunk for slot
    }

#define STAGE(buf, kt) do {                                                        \
    _Pragma("unroll")                                                              \
    for (int j = 0; j < 2; j++) {                                                  \
        const __hip_bfloat16* ga = A + (size_t)(mtile * BM + s_row[j]) * KDIM      \
                                     + (kt) * BK + s_goff[j];                      \
        __builtin_amdgcn_global_load_lds((const GLOBAL_AS void*)ga,                \
            (LDS_AS void*)&sm[buf][0][(w * 16 + j * 8) * BK], 16, 0, 0);           \
        const __hip_bfloat16* gb = B + (size_t)(ntile * BN + s_row[j]) * KDIM      \
                                     + (kt) * BK + s_goff[j];                      \
        __builtin_amdgcn_global_load_lds((const GLOBAL_AS void*)gb,                \
            (LDS_AS void*)&sm[buf][1][(w * 16 + j * 8) * BK], 16, 0, 0);           \
    }                                                                              \
} while (0)

    // --- fragment LDS element offsets (swizzled reads) ---
    // 16x16x32 frag at k-chunk = wk*32: lane holds [row][k=(lane>>4)*8 ..+8]
    int a_off[4], b_off[4];
#pragma unroll
    for (int m = 0; m < 4; m++) {
        int row = wr * 64 + m * 16 + (lane & 15);
        int c = wk * 4 + (lane >> 4);
        a_off[m] = row * BK + (c ^ (row & 7)) * 8;
    }
#pragma unroll
    for (int n = 0; n < 4; n++) {
        int row = wc * 64 + n * 16 + (lane & 15);
        int c = wk * 4 + (lane >> 4);
        b_off[n] = row * BK + (c ^ (row & 7)) * 8;
    }

    f32x4 acc[4][4] = {};

#define COMPUTE(buf) do {                                                          \
    short8 af[4], bfv[4];                                                          \
    _Pragma("unroll")                                                              \
    for (int m = 0; m < 4; m++)                                                    \
        af[m] = *(const short8*)&sm[buf][0][a_off[m]];                             \
    _Pragma("unroll")                                                              \
    for (int n = 0; n < 4; n++)                                                    \
        bfv[n] = *(const short8*)&sm[buf][1][b_off[n]];                            \
    _Pragma("unroll")                                                              \
    for (int m = 0; m < 4; m++)                                                    \
        _Pragma("unroll")                                                          \
        for (int n = 0; n < 4; n++)                                                \
            acc[m][n] = __builtin_amdgcn_mfma_f32_16x16x32_bf16(                   \
                af[m], bfv[n], acc[m][n], 0, 0, 0);                                \
} while (0)

    const int NT = KDIM / BK;  // 64 (NT % 4 == 0)
    STAGE(0, 0);
    STAGE(1, 1);

    for (int t = 0; t < NT; t++) {
        const int cur = t & 3;
        // STAGE(t+2) writes (t+2)%4; concurrent readers are at (t-1)%4 and
        // t%4 -> WAR distances 3 and 2, never 0: no trailing barrier needed.
        if (t + 2 < NT) {
            STAGE((t + 2) & 3, t + 2);
            // per-wave 4 loads/stage; stages t+1,t+2 in flight (8) ->
            // oldest stage (t) has landed.
            asm volatile("s_waitcnt vmcnt(8)" ::: "memory");
        } else if (t + 1 < NT) {
            asm volatile("s_waitcnt vmcnt(4)" ::: "memory");
        } else {
            asm volatile("s_waitcnt vmcnt(0)" ::: "memory");
        }
        HARD_BARRIER();        // single barrier: every wave's stage(t) landed
        COMPUTE(cur);          // WAR protection for restage = buffer distance
    }

    // --- cross-wk reduction through LDS ---
    // Post-loop barrier: laggard waves may still be reading bufs 0/1 from
    // their last COMPUTE while fast waves would overwrite them below.
    HARD_BARRIER();
    // wk=1 wave writes its 64 acc floats lane-minor (16B/lane, conflict-free):
    // float offset = pair*4096 + (m*4+n)*256 + lane*4   (64 KB in bufs 0-1)
    float* red = (float*)&sm[0][0][0];
    const int pair = wr * 2 + wc;            // 0..3
    if (wk == 1) {
#pragma unroll
        for (int m = 0; m < 4; m++) {
#pragma unroll
            for (int n = 0; n < 4; n++) {
                *(f32x4*)&red[pair * 4096 + (m * 4 + n) * 256 + lane * 4] =
                    acc[m][n];
            }
        }
    }
    HARD_BARRIER();   // includes lgkmcnt(0) drain -> writes visible
    if (wk == 0) {
        // epilogue: C/D layout col = lane&15, row = (lane>>4)*4 + r
        const int rbase = mtile * BM + wr * 64 + ((lane >> 4) << 2);
        const int cbase = ntile * BN + wc * 64 + (lane & 15);
#pragma unroll
        for (int m = 0; m < 4; m++) {
#pragma unroll
            for (int n = 0; n < 4; n++) {
                f32x4 other =
                    *(const f32x4*)&red[pair * 4096 + (m * 4 + n) * 256 + lane * 4];
                f32x4 v = acc[m][n] + other;
#pragma unroll
                for (int r = 0; r < 4; r++) {
                    C[(size_t)(rbase + m * 16 + r) * NDIM + cbase + n * 16] = v[r];
                }
            }
        }
    }
#undef STAGE
#undef COMPUTE
}

// ---------------------------------------------------------------------------
// Fallback (only if ws too small): textbook fp32 tiled GEMM with inline dequant
// ---------------------------------------------------------------------------
__global__ void fallback_kernel(const float* __restrict__ x,
                                const float* __restrict__ w0,
                                const int* __restrict__ nf4_idx,
                                const float* __restrict__ sp,
                                const float* __restrict__ zpp,
                                float* __restrict__ out)
{
    __shared__ float As[16][16], Bs[16][17];
    const int tx = threadIdx.x, ty = threadIdx.y;
    const int n0 = blockIdx.x * 16, m0 = blockIdx.y * 16;
    const float s = sp[0], zp = zpp[0];
    float acc = 0.0f;
    for (int k0 = 0; k0 < KDIM; k0 += 16) {
        As[ty][tx] = x[(size_t)(m0 + ty) * KDIM + k0 + tx];
        int id = nf4_idx[(size_t)(n0 + ty) * KDIM + k0 + tx];
        Bs[ty][tx] = w0[(size_t)(n0 + ty) * KDIM + k0 + tx] + c_nf4[id] * s + zp;
        __syncthreads();
#pragma unroll
        for (int j = 0; j < 16; j++) acc += As[ty][j] * Bs[tx][j];
        __syncthreads();
    }
    out[(size_t)(m0 + ty) * NDIM + n0 + tx] = acc;
}

extern "C" void kernel_launch(void* const* d_in, const int* in_sizes, int n_in,
                              void* d_out, int out_size, void* d_ws, size_t ws_size,
                              hipStream_t stream) {
    const float* x = (const float*)d_in[0];
    const float* w0 = (const float*)d_in[1];
    const int* nf4_idx = (const int*)d_in[2];
    const float* scale = (const float*)d_in[3];
    const float* zp = (const float*)d_in[4];
    float* out = (float*)d_out;

    const size_t wc_bytes = (size_t)NDIM * KDIM * 2;       // 33,554,432
    const size_t xb_bytes = (size_t)MDIM * KDIM * 2;       //  8,388,608

    if (ws_size >= wc_bytes + xb_bytes) {
        __hip_bfloat16* Wc = (__hip_bfloat16*)d_ws;
        __hip_bfloat16* xb = (__hip_bfloat16*)((char*)d_ws + wc_bytes);
        prep_kernel<<<W_BLOCKS + X_BLOCKS, 256, 0, stream>>>(
            x, w0, nf4_idx, scale, zp, Wc, xb);
        gemm_kernel<<<(MDIM / BM) * (NDIM / BN), 512, 0, stream>>>(xb, Wc, out);
    } else {
        fallback_kernel<<<dim3(NDIM / 16, MDIM / 16), dim3(16, 16), 0, stream>>>(
            x, w0, nf4_idx, scale, zp, out);
    }
}